// Round 5
// baseline (49.042 us; speedup 1.0000x reference)
//
#include <hip/hip_runtime.h>
#include <math.h>

#define NB 16
#define DM 128
#define BM 256
#define ZSTRIDE 68   // halves per Z row: 136 B (8B-aligned b64 access)

typedef _Float16 half8  __attribute__((ext_vector_type(8)));
typedef _Float16 half4v __attribute__((ext_vector_type(4)));
typedef _Float16 half2v __attribute__((ext_vector_type(2)));
typedef __fp16   fp16x2 __attribute__((ext_vector_type(2)));
typedef float    f32x4  __attribute__((ext_vector_type(4)));

__device__ __forceinline__ float frcp_(float x) { return __builtin_amdgcn_rcpf(x); }
__device__ __forceinline__ float softplus_fast(float x) {
    return fmaxf(x, 0.0f) + __logf(1.0f + __expf(-fabsf(x)));
}
__device__ __forceinline__ float sigmoid_fast(float x) {
    return frcp_(1.0f + __expf(-x));
}
__device__ __forceinline__ void softmax16_m(float* z) {
    float m = z[0];
#pragma unroll
    for (int k = 1; k < NB; k++) m = fmaxf(m, z[k]);
    float s = 0.0f;
#pragma unroll
    for (int k = 0; k < NB; k++) { z[k] = __expf(z[k] - m); s += z[k]; }
    float r = frcp_(s);
#pragma unroll
    for (int k = 0; k < NB; k++) z[k] *= r;
}
// outer softmax: inputs in [0,1] (inner softmax output) -> no max-subtract
__device__ __forceinline__ void softmax16_nm(float* z) {
    float s = 0.0f;
#pragma unroll
    for (int k = 0; k < NB; k++) { z[k] = __expf(z[k]); s += z[k]; }
    float r = frcp_(s);
#pragma unroll
    for (int k = 0; k < NB; k++) z[k] *= r;
}

__device__ __forceinline__ half2v pk_(float lo, float hi) {
    fp16x2 p = __builtin_amdgcn_cvt_pkrtz(lo, hi);
    return __builtin_bit_cast(half2v, p);
}
__device__ __forceinline__ half8 cvt8(float4 a0, float4 a1) {
    half2v p0 = pk_(a0.x, a0.y);
    half2v p1 = pk_(a0.z, a0.w);
    half2v p2 = pk_(a1.x, a1.y);
    half2v p3 = pk_(a1.z, a1.w);
    half8 f;
    f[0] = p0[0]; f[1] = p0[1]; f[2] = p1[0]; f[3] = p1[1];
    f[4] = p2[0]; f[5] = p2[1]; f[6] = p3[0]; f[7] = p3[1];
    return f;
}

struct Abuf { float4 v[8]; };

__device__ __forceinline__ void issueA(Abuf& b, const float* cr) {
#pragma unroll
    for (int s = 0; s < 4; s++) {
        b.v[2 * s]     = *(const float4*)(cr + 32 * s);
        b.v[2 * s + 1] = *(const float4*)(cr + 32 * s + 4);
    }
}
__device__ __forceinline__ void cvtA(const Abuf& b, half8 Af[4]) {
#pragma unroll
    for (int s = 0; s < 4; s++) Af[s] = cvt8(b.v[2 * s], b.v[2 * s + 1]);
}
__device__ __forceinline__ void mfmaStore(const half8 Af[4], const half8 Bf[4][4],
                                          _Float16* zp) {
    f32x4 a0 = {0.f,0.f,0.f,0.f}, a1 = a0, a2 = a0, a3 = a0;
#pragma unroll
    for (int s = 0; s < 4; s++) {
        a0 = __builtin_amdgcn_mfma_f32_16x16x32_f16(Af[s], Bf[0][s], a0, 0, 0, 0);
        a1 = __builtin_amdgcn_mfma_f32_16x16x32_f16(Af[s], Bf[1][s], a1, 0, 0, 0);
        a2 = __builtin_amdgcn_mfma_f32_16x16x32_f16(Af[s], Bf[2][s], a2, 0, 0, 0);
        a3 = __builtin_amdgcn_mfma_f32_16x16x32_f16(Af[s], Bf[3][s], a3, 0, 0, 0);
    }
    // D layout: col = lane&15, row = (lane>>4)*4 + reg  [m89/m91]
    // interleaved Z columns: pos = (col&15)*4 + t  <=>  n = t*16 + col
#pragma unroll
    for (int r = 0; r < 4; r++) {
        half2v p0 = pk_(a0[r], a1[r]);
        half2v p1 = pk_(a2[r], a3[r]);
        half4v w;
        w[0] = p0[0]; w[1] = p0[1]; w[2] = p1[0]; w[3] = p1[1];
        *(half4v*)(zp + (size_t)r * ZSTRIDE) = w;
    }
}

__global__ __launch_bounds__(256, 3) void spline_mfma(
    const float* __restrict__ xin, const float* __restrict__ cond,
    const float* __restrict__ Ww, const float* __restrict__ bw,
    const float* __restrict__ Wh, const float* __restrict__ bh,
    const float* __restrict__ Wd, const float* __restrict__ bd,
    const float* __restrict__ Wl, const float* __restrict__ bl,
    float* __restrict__ out, float* __restrict__ lad, int N)
{
    __shared__ __align__(16) _Float16 Z[BM * ZSTRIDE];

    const int tid  = threadIdx.x;
    const int wave = tid >> 6;
    const int lane = tid & 63;
    const int l15  = lane & 15;
    const int lg   = lane >> 4;
    const size_t blockRow = (size_t)blockIdx.x * BM;

    // epilogue x: issue early (HBM)
    const size_t gi = blockRow + tid;
    float x = xin[gi < (size_t)N ? gi : 0];

    // A-row pointer for chunk c (rows are HBM/L3; deepest-latency loads first)
    auto aRow = [&](int c) -> const float* {
        size_t gr = blockRow + (size_t)(wave * 64 + c * 16 + l15);
        if (gr >= (size_t)N) gr = (size_t)N - 1;
        return cond + gr * DM + lg * 8;
    };

    Abuf A0, A1;
    issueA(A0, aRow(0));   // chunks 0+1 in flight before anything else
    issueA(A1, aRow(1));

    // ---- B fragments: W'[64][128] -> 16 half8 frags (VGPR-resident) ----
    // B[k][n] = W'[n][k]; lane holds col n=l15, k = 32*s + lg*8 + j
    // (identical k<->elem formula as A => HW k-permutation cancels)
    half8 Bf[4][4];
#pragma unroll
    for (int t = 0; t < 4; t++) {
        const float* Wt = (t == 0) ? Ww : (t == 1) ? Wh : (t == 2) ? Wl : Wd;
        const bool valid = (t < 3) || (l15 < 15);
        const float* src = Wt + (size_t)(valid ? l15 : 0) * DM;
#pragma unroll
        for (int s = 0; s < 4; s++) {
            const int k0 = 32 * s + lg * 8;
            if (valid) {
                float4 a0 = *(const float4*)(src + k0);
                float4 a1 = *(const float4*)(src + k0 + 4);
                Bf[t][s] = cvt8(a0, a1);
            } else {
                half8 f;
                f[0]=f[1]=f[2]=f[3]=f[4]=f[5]=f[6]=f[7] = (_Float16)0.0f;
                Bf[t][s] = f;
            }
        }
    }

    // ---- software-pipelined MFMA main (2-chunk-deep register dbuf) ----
    _Float16* zbase = &Z[(size_t)(wave * 64 + lg * 4) * ZSTRIDE + l15 * 4];
    half8 Af[4];
    cvtA(A0, Af);               // waits on chunk0 loads
    issueA(A0, aRow(2));        // refill while chunk0 computes
    mfmaStore(Af, Bf, zbase + (size_t)(0 * 16) * ZSTRIDE);
    cvtA(A1, Af);
    issueA(A1, aRow(3));
    mfmaStore(Af, Bf, zbase + (size_t)(1 * 16) * ZSTRIDE);
    cvtA(A0, Af);
    mfmaStore(Af, Bf, zbase + (size_t)(2 * 16) * ZSTRIDE);
    cvtA(A1, Af);
    mfmaStore(Af, Bf, zbase + (size_t)(3 * 16) * ZSTRIDE);

    // Wave-local LDS dependency only (wave w writes rows [64w,64w+64), thread
    // tid reads row tid of its own wave) -> no __syncthreads; drain DS queue.
    __builtin_amdgcn_sched_barrier(0);
    asm volatile("s_waitcnt lgkmcnt(0)" ::: "memory");
    __builtin_amdgcn_sched_barrier(0);

    // ---- epilogue: 1 thread = 1 row ----
    if (gi >= (size_t)N) return;

    float zw[NB], zh[NB], zl[NB], zd[NB - 1];
    const half4v* zr4 = (const half4v*)&Z[(size_t)tid * ZSTRIDE];
#pragma unroll
    for (int j = 0; j < NB; j++) {
        half4v v = zr4[j];   // interleaved: (zw[j], zh[j], zl[j], zd[j])
        zw[j] = (float)v[0] + bw[j];
        zh[j] = (float)v[1] + bh[j];
        zl[j] = (float)v[2] + bl[j];
        if (j < NB - 1) zd[j] = (float)v[3] + bd[j];
    }

    float xc = fminf(fmaxf(x, -20.0f), 20.0f);

    // widths: module softmax, then spline softmax
    softmax16_m(zw);
    softmax16_nm(zw);
    const float scale = (1.0f - 1e-3f * NB);
    float cw[NB + 1];
    cw[0] = -20.0f;
    float cum = 0.0f;
#pragma unroll
    for (int k = 0; k < NB; k++) {
        cum += 1e-3f + scale * zw[k];
        cw[k + 1] = 40.0f * cum - 20.0f;
    }
    cw[NB] = 20.0f;

    // heights
    softmax16_m(zh);
    softmax16_nm(zh);
    float ch[NB + 1];
    ch[0] = -20.0f;
    cum = 0.0f;
#pragma unroll
    for (int k = 0; k < NB; k++) {
        cum += 1e-3f + scale * zh[k];
        ch[k + 1] = 40.0f * cum - 20.0f;
    }
    ch[NB] = 20.0f;

    // ---- fused searchsorted + gather: one take-predicate chain ----
    float in_cw = cw[0], cw_hi = cw[1], in_ch = ch[0], ch_hi = ch[1];
    float zl_sel = zl[0], zd_lo = zd[0], zd_hi = zd[0];
#pragma unroll
    for (int k = 1; k < NB; k++) {
        bool take = (xc >= cw[k]);
        in_cw  = take ? cw[k]     : in_cw;
        cw_hi  = take ? cw[k + 1] : cw_hi;
        in_ch  = take ? ch[k]     : in_ch;
        ch_hi  = take ? ch[k + 1] : ch_hi;
        zl_sel = take ? zl[k]     : zl_sel;
        zd_lo  = take ? zd[k - 1] : zd_lo;
        zd_hi  = take ? zd[(k < NB - 1) ? k : NB - 2] : zd_hi;  // k=15 dummy (masked)
    }
    bool firstbin = (xc <  cw[1]);
    bool lastbin  = (xc >= cw[NB - 1]);

    float in_bw = cw_hi - in_cw;
    float in_h  = ch_hi - in_ch;

    // d = MIN_D + softplus([edge, softplus(zd), edge]); edge -> exactly 1.0
    float dk  = firstbin ? 1.0f : (1e-3f + softplus_fast(softplus_fast(zd_lo)));
    float dk1 = lastbin  ? 1.0f : (1e-3f + softplus_fast(softplus_fast(zd_hi)));

    // lambda (double sigmoid)
    float ul  = sigmoid_fast(zl_sel);
    float lam = 0.95f * sigmoid_fast(ul) + 0.025f;

    // rational-linear spline (wa = 1)
    float rbw = frcp_(in_bw);
    float in_delta = in_h * rbw;
    float wb = sqrtf(dk * frcp_(dk1));
    float wc = (lam * dk + (1.0f - lam) * wb * dk1) * frcp_(in_delta);
    float ya = in_ch;
    float yb = in_h + in_ch;
    float yc = ((1.0f - lam) * ya + lam * wb * yb) * frcp_((1.0f - lam) + lam * wb);
    float theta = (xc - in_cw) * rbw;
    bool mlt = (theta <= lam);

    float num = mlt ? (ya * (lam - theta) + wc * yc * theta)
                    : (wc * yc * (1.0f - theta) + wb * yb * (theta - lam));
    float den = mlt ? ((lam - theta) + wc * theta)
                    : (wc * (1.0f - theta) + wb * (theta - lam));
    float sout = num * frcp_(den);
    float dnum = (mlt ? (wc * lam * (yc - ya))
                      : (wb * wc * (1.0f - lam) * (yb - yc))) * rbw;
    float slad = __logf(dnum) - 2.0f * __logf(fabsf(den));

    bool inside = (x >= -20.0f) && (x <= 20.0f);
    out[gi] = inside ? sout : x;
    lad[gi] = inside ? slad : 0.0f;
}

extern "C" void kernel_launch(void* const* d_in, const int* in_sizes, int n_in,
                              void* d_out, int out_size, void* d_ws, size_t ws_size,
                              hipStream_t stream) {
    const float* xin  = (const float*)d_in[0];
    const float* cond = (const float*)d_in[1];
    const float* Ww   = (const float*)d_in[2];
    const float* bwp  = (const float*)d_in[3];
    const float* Wh   = (const float*)d_in[4];
    const float* bhp  = (const float*)d_in[5];
    const float* Wd   = (const float*)d_in[6];
    const float* bdp  = (const float*)d_in[7];
    const float* Wl   = (const float*)d_in[8];
    const float* blp  = (const float*)d_in[9];
    int N = in_sizes[0];  // 32*8192
    float* out = (float*)d_out;
    float* lad = out + N;
    int grid = (N + BM - 1) / BM;
    hipLaunchKernelGGL(spline_mfma, dim3(grid), dim3(256), 0, stream,
                       xin, cond, Ww, bwp, Wh, bhp, Wd, bdp, Wl, blp, out, lad, N);
}

// Round 6
// 41.628 us; speedup vs baseline: 1.1781x; 1.1781x over previous
//
#include <hip/hip_runtime.h>
#include <math.h>

#define NB 16
#define DM 128
#define BM 256
#define ZSTRIDE 68   // halves per Z row: 136 B (8B-aligned b64 access, bank-spread)

typedef _Float16 half8  __attribute__((ext_vector_type(8)));
typedef _Float16 half4v __attribute__((ext_vector_type(4)));
typedef _Float16 half2v __attribute__((ext_vector_type(2)));
typedef __fp16   fp16x2 __attribute__((ext_vector_type(2)));
typedef float    f32x4  __attribute__((ext_vector_type(4)));

__device__ __forceinline__ float frcp_(float x) { return __builtin_amdgcn_rcpf(x); }
__device__ __forceinline__ float softplus_fast(float x) {
    return fmaxf(x, 0.0f) + __logf(1.0f + __expf(-fabsf(x)));
}
__device__ __forceinline__ float sigmoid_fast(float x) {
    return frcp_(1.0f + __expf(-x));
}
__device__ __forceinline__ void softmax16_m(float* z) {
    float m = z[0];
#pragma unroll
    for (int k = 1; k < NB; k++) m = fmaxf(m, z[k]);
    float s = 0.0f;
#pragma unroll
    for (int k = 0; k < NB; k++) { z[k] = __expf(z[k] - m); s += z[k]; }
    float r = frcp_(s);
#pragma unroll
    for (int k = 0; k < NB; k++) z[k] *= r;
}
// outer softmax: inputs in [0,1] (inner softmax output) -> no max-subtract
__device__ __forceinline__ void softmax16_nm(float* z) {
    float s = 0.0f;
#pragma unroll
    for (int k = 0; k < NB; k++) { z[k] = __expf(z[k]); s += z[k]; }
    float r = frcp_(s);
#pragma unroll
    for (int k = 0; k < NB; k++) z[k] *= r;
}

__device__ __forceinline__ half2v pk_(float lo, float hi) {
    fp16x2 p = __builtin_amdgcn_cvt_pkrtz(lo, hi);
    return __builtin_bit_cast(half2v, p);
}
__device__ __forceinline__ half8 cvt8(float4 a0, float4 a1) {
    half2v p0 = pk_(a0.x, a0.y);
    half2v p1 = pk_(a0.z, a0.w);
    half2v p2 = pk_(a1.x, a1.y);
    half2v p3 = pk_(a1.z, a1.w);
    half8 f;
    f[0] = p0[0]; f[1] = p0[1]; f[2] = p1[0]; f[3] = p1[1];
    f[4] = p2[0]; f[5] = p2[1]; f[6] = p3[0]; f[7] = p3[1];
    return f;
}

// ---- named-variable pipeline macros (NO addressable aggregates) ----
// half-chunk h of a 16-row chunk: 4 dwordx4 at koff = 64*h + {0,4,32,36}
#define ISSUE(P, cr, koff)                                  \
    P##0 = *(const float4*)((cr) + (koff));                 \
    P##1 = *(const float4*)((cr) + (koff) + 4);             \
    P##2 = *(const float4*)((cr) + (koff) + 32);            \
    P##3 = *(const float4*)((cr) + (koff) + 36);

#define CVT2(P, lo, hi)                                     \
    lo = cvt8(P##0, P##1);                                  \
    hi = cvt8(P##2, P##3);

#define MFMA_S(af, s)                                                           \
    acc0 = __builtin_amdgcn_mfma_f32_16x16x32_f16(af, B0##s, acc0, 0, 0, 0);    \
    acc1 = __builtin_amdgcn_mfma_f32_16x16x32_f16(af, B1##s, acc1, 0, 0, 0);    \
    acc2 = __builtin_amdgcn_mfma_f32_16x16x32_f16(af, B2##s, acc2, 0, 0, 0);    \
    acc3 = __builtin_amdgcn_mfma_f32_16x16x32_f16(af, B3##s, acc3, 0, 0, 0);

// D layout: col = lane&15, row = (lane>>4)*4 + reg  [m89/m91]
// interleaved Z: pos = (col)*4 + t  <=>  net n = t*16 + col
#define STOREZ(c) {                                                             \
    _Float16* zpw = zbase + (size_t)((c) * 16) * ZSTRIDE;                       \
    _Pragma("unroll")                                                           \
    for (int r = 0; r < 4; r++) {                                               \
        half2v p0 = pk_(acc0[r], acc1[r]);                                      \
        half2v p1 = pk_(acc2[r], acc3[r]);                                      \
        half4v w; w[0] = p0[0]; w[1] = p0[1]; w[2] = p1[0]; w[3] = p1[1];       \
        *(half4v*)(zpw + (size_t)r * ZSTRIDE) = w;                              \
    } }

#define RESET_ACC  acc0 = zf4; acc1 = zf4; acc2 = zf4; acc3 = zf4;

// B frag staging: row l15 of Wt (t-th param matrix), k = 32*s + lg*8 + j
#define STAGE_B(Wt, isWd, Q0, Q1, Q2, Q3) {                                     \
    const bool val = (!(isWd)) || (l15 < 15);                                   \
    const float* srcl = (Wt) + (size_t)(val ? l15 : 0) * DM + lg * 8;           \
    float4 q0 = *(const float4*)(srcl + 0),  q1 = *(const float4*)(srcl + 4);   \
    float4 q2 = *(const float4*)(srcl + 32), q3 = *(const float4*)(srcl + 36);  \
    float4 q4 = *(const float4*)(srcl + 64), q5 = *(const float4*)(srcl + 68);  \
    float4 q6 = *(const float4*)(srcl + 96), q7 = *(const float4*)(srcl + 100); \
    Q0 = val ? cvt8(q0, q1) : hz;                                               \
    Q1 = val ? cvt8(q2, q3) : hz;                                               \
    Q2 = val ? cvt8(q4, q5) : hz;                                               \
    Q3 = val ? cvt8(q6, q7) : hz; }

__global__ __launch_bounds__(256, 3) void spline_mfma(
    const float* __restrict__ xin, const float* __restrict__ cond,
    const float* __restrict__ Ww, const float* __restrict__ bw,
    const float* __restrict__ Wh, const float* __restrict__ bh,
    const float* __restrict__ Wd, const float* __restrict__ bd,
    const float* __restrict__ Wl, const float* __restrict__ bl,
    float* __restrict__ out, float* __restrict__ lad, int N)
{
    __shared__ __align__(16) _Float16 Z[BM * ZSTRIDE];

    const int tid  = threadIdx.x;
    const int wave = tid >> 6;
    const int lane = tid & 63;
    const int l15  = lane & 15;
    const int lg   = lane >> 4;
    const size_t blockRow = (size_t)blockIdx.x * BM;

    // epilogue x: issue early (HBM)
    const size_t gi = blockRow + tid;
    float x = xin[gi < (size_t)N ? gi : 0];

    // chunk row pointers (clamped); lane reads row (wave*64 + c*16 + l15)
    size_t gr0 = blockRow + (size_t)(wave * 64 + l15);
    size_t gr1 = gr0 + 16, gr2 = gr0 + 32, gr3 = gr0 + 48;
    if (gr0 >= (size_t)N) gr0 = (size_t)N - 1;
    if (gr1 >= (size_t)N) gr1 = (size_t)N - 1;
    if (gr2 >= (size_t)N) gr2 = (size_t)N - 1;
    if (gr3 >= (size_t)N) gr3 = (size_t)N - 1;
    const float* cr0 = cond + gr0 * DM + lg * 8;
    const float* cr1 = cond + gr1 * DM + lg * 8;
    const float* cr2 = cond + gr2 * DM + lg * 8;
    const float* cr3 = cond + gr3 * DM + lg * 8;

    // prologue: chunk0's two half-chunks in flight before anything else
    float4 X0, X1, X2, X3, Y0, Y1, Y2, Y3;
    ISSUE(X, cr0, 0)
    ISSUE(Y, cr0, 64)

    // ---- B fragments: 16 named half8 (k<->elem formula identical to A) ----
    half8 hz;
    hz[0]=hz[1]=hz[2]=hz[3]=hz[4]=hz[5]=hz[6]=hz[7] = (_Float16)0.0f;
    half8 B00, B01, B02, B03, B10, B11, B12, B13,
          B20, B21, B22, B23, B30, B31, B32, B33;
    STAGE_B(Ww, false, B00, B01, B02, B03)
    STAGE_B(Wh, false, B10, B11, B12, B13)
    STAGE_B(Wl, false, B20, B21, B22, B23)
    STAGE_B(Wd, true,  B30, B31, B32, B33)

    const f32x4 zf4 = {0.f, 0.f, 0.f, 0.f};
    f32x4 acc0 = zf4, acc1 = zf4, acc2 = zf4, acc3 = zf4;
    half8 af0, af1;
    _Float16* zbase = &Z[(size_t)(wave * 64 + lg * 4) * ZSTRIDE + l15 * 4];

    // ---- software-pipelined main: 8 half-chunks, 2-deep X/Y rotation ----
    CVT2(X, af0, af1)           // waits chunk0-h0; Y + issued stay in flight
    ISSUE(X, cr1, 0)            // chunk1-h0
    MFMA_S(af0, 0) MFMA_S(af1, 1)
    CVT2(Y, af0, af1)
    ISSUE(Y, cr1, 64)           // chunk1-h1
    MFMA_S(af0, 2) MFMA_S(af1, 3)
    STOREZ(0) RESET_ACC

    CVT2(X, af0, af1)
    ISSUE(X, cr2, 0)
    MFMA_S(af0, 0) MFMA_S(af1, 1)
    CVT2(Y, af0, af1)
    ISSUE(Y, cr2, 64)
    MFMA_S(af0, 2) MFMA_S(af1, 3)
    STOREZ(1) RESET_ACC

    CVT2(X, af0, af1)
    ISSUE(X, cr3, 0)
    MFMA_S(af0, 0) MFMA_S(af1, 1)
    CVT2(Y, af0, af1)
    ISSUE(Y, cr3, 64)
    MFMA_S(af0, 2) MFMA_S(af1, 3)
    STOREZ(2) RESET_ACC

    CVT2(X, af0, af1)
    MFMA_S(af0, 0) MFMA_S(af1, 1)
    CVT2(Y, af0, af1)
    MFMA_S(af0, 2) MFMA_S(af1, 3)
    STOREZ(3)

    // Wave-local LDS dependency only (wave w writes rows [64w,64w+64), thread
    // tid reads row tid of its own wave) -> no __syncthreads; drain DS queue.
    __builtin_amdgcn_sched_barrier(0);
    asm volatile("s_waitcnt lgkmcnt(0)" ::: "memory");
    __builtin_amdgcn_sched_barrier(0);

    // ---- epilogue: 1 thread = 1 row (proven round-4 path) ----
    if (gi >= (size_t)N) return;

    float zw[NB], zh[NB], zl[NB], zd[NB - 1];
    const half4v* zr4 = (const half4v*)&Z[(size_t)tid * ZSTRIDE];
#pragma unroll
    for (int j = 0; j < NB; j++) {
        half4v v = zr4[j];   // interleaved: (zw[j], zh[j], zl[j], zd[j])
        zw[j] = (float)v[0] + bw[j];
        zh[j] = (float)v[1] + bh[j];
        zl[j] = (float)v[2] + bl[j];
        if (j < NB - 1) zd[j] = (float)v[3] + bd[j];
    }

    float xc = fminf(fmaxf(x, -20.0f), 20.0f);

    // widths: module softmax, then spline softmax
    softmax16_m(zw);
    softmax16_nm(zw);
    const float scale = (1.0f - 1e-3f * NB);
    float cw[NB + 1];
    cw[0] = -20.0f;
    float cum = 0.0f;
#pragma unroll
    for (int k = 0; k < NB; k++) {
        cum += 1e-3f + scale * zw[k];
        cw[k + 1] = 40.0f * cum - 20.0f;
    }
    cw[NB] = 20.0f;

    // heights
    softmax16_m(zh);
    softmax16_nm(zh);
    float ch[NB + 1];
    ch[0] = -20.0f;
    cum = 0.0f;
#pragma unroll
    for (int k = 0; k < NB; k++) {
        cum += 1e-3f + scale * zh[k];
        ch[k + 1] = 40.0f * cum - 20.0f;
    }
    ch[NB] = 20.0f;

    // fused searchsorted + gather: one take-predicate chain
    float in_cw = cw[0], cw_hi = cw[1], in_ch = ch[0], ch_hi = ch[1];
    float zl_sel = zl[0], zd_lo = zd[0], zd_hi = zd[0];
#pragma unroll
    for (int k = 1; k < NB; k++) {
        bool take = (xc >= cw[k]);
        in_cw  = take ? cw[k]     : in_cw;
        cw_hi  = take ? cw[k + 1] : cw_hi;
        in_ch  = take ? ch[k]     : in_ch;
        ch_hi  = take ? ch[k + 1] : ch_hi;
        zl_sel = take ? zl[k]     : zl_sel;
        zd_lo  = take ? zd[k - 1] : zd_lo;
        zd_hi  = take ? zd[(k < NB - 1) ? k : NB - 2] : zd_hi;  // k=15 dummy (masked)
    }
    bool firstbin = (xc <  cw[1]);
    bool lastbin  = (xc >= cw[NB - 1]);

    float in_bw = cw_hi - in_cw;
    float in_h  = ch_hi - in_ch;

    // d = MIN_D + softplus([edge, softplus(zd), edge]); edge -> exactly 1.0
    float dk  = firstbin ? 1.0f : (1e-3f + softplus_fast(softplus_fast(zd_lo)));
    float dk1 = lastbin  ? 1.0f : (1e-3f + softplus_fast(softplus_fast(zd_hi)));

    // lambda (double sigmoid)
    float ul  = sigmoid_fast(zl_sel);
    float lam = 0.95f * sigmoid_fast(ul) + 0.025f;

    // rational-linear spline (wa = 1)
    float rbw = frcp_(in_bw);
    float in_delta = in_h * rbw;
    float wb = sqrtf(dk * frcp_(dk1));
    float wc = (lam * dk + (1.0f - lam) * wb * dk1) * frcp_(in_delta);
    float ya = in_ch;
    float yb = in_h + in_ch;
    float yc = ((1.0f - lam) * ya + lam * wb * yb) * frcp_((1.0f - lam) + lam * wb);
    float theta = (xc - in_cw) * rbw;
    bool mlt = (theta <= lam);

    float num = mlt ? (ya * (lam - theta) + wc * yc * theta)
                    : (wc * yc * (1.0f - theta) + wb * yb * (theta - lam));
    float den = mlt ? ((lam - theta) + wc * theta)
                    : (wc * (1.0f - theta) + wb * (theta - lam));
    float sout = num * frcp_(den);
    float dnum = (mlt ? (wc * lam * (yc - ya))
                      : (wb * wc * (1.0f - lam) * (yb - yc))) * rbw;
    float slad = __logf(dnum) - 2.0f * __logf(fabsf(den));

    bool inside = (x >= -20.0f) && (x <= 20.0f);
    out[gi] = inside ? sout : x;
    lad[gi] = inside ? slad : 0.0f;
}

extern "C" void kernel_launch(void* const* d_in, const int* in_sizes, int n_in,
                              void* d_out, int out_size, void* d_ws, size_t ws_size,
                              hipStream_t stream) {
    const float* xin  = (const float*)d_in[0];
    const float* cond = (const float*)d_in[1];
    const float* Ww   = (const float*)d_in[2];
    const float* bwp  = (const float*)d_in[3];
    const float* Wh   = (const float*)d_in[4];
    const float* bhp  = (const float*)d_in[5];
    const float* Wd   = (const float*)d_in[6];
    const float* bdp  = (const float*)d_in[7];
    const float* Wl   = (const float*)d_in[8];
    const float* blp  = (const float*)d_in[9];
    int N = in_sizes[0];  // 32*8192
    float* out = (float*)d_out;
    float* lad = out + N;
    int grid = (N + BM - 1) / BM;
    hipLaunchKernelGGL(spline_mfma, dim3(grid), dim3(256), 0, stream,
                       xin, cond, Ww, bwp, Wh, bhp, Wd, bdp, Wl, blp, out, lad, N);
}

// Round 7
// 39.079 us; speedup vs baseline: 1.2550x; 1.0652x over previous
//
#include <hip/hip_runtime.h>
#include <math.h>

#define NB 16
#define DM 128
#define BM 256
#define ZSTRIDE 68   // halves per Z row: 136 B (8B-aligned b64 access, bank-spread)

typedef _Float16 half8  __attribute__((ext_vector_type(8)));
typedef _Float16 half4v __attribute__((ext_vector_type(4)));
typedef _Float16 half2v __attribute__((ext_vector_type(2)));
typedef __fp16   fp16x2 __attribute__((ext_vector_type(2)));
typedef float    f32x4  __attribute__((ext_vector_type(4)));

__device__ __forceinline__ float frcp_(float x) { return __builtin_amdgcn_rcpf(x); }
__device__ __forceinline__ float softplus_fast(float x) {
    return fmaxf(x, 0.0f) + __logf(1.0f + __expf(-fabsf(x)));
}
__device__ __forceinline__ float sigmoid_fast(float x) {
    return frcp_(1.0f + __expf(-x));
}
__device__ __forceinline__ void softmax16_m(float* z) {
    float m = z[0];
#pragma unroll
    for (int k = 1; k < NB; k++) m = fmaxf(m, z[k]);
    float s = 0.0f;
#pragma unroll
    for (int k = 0; k < NB; k++) { z[k] = __expf(z[k] - m); s += z[k]; }
    float r = frcp_(s);
#pragma unroll
    for (int k = 0; k < NB; k++) z[k] *= r;
}
// outer softmax: inputs in [0,1] (inner softmax output) -> no max-subtract
__device__ __forceinline__ void softmax16_nm(float* z) {
    float s = 0.0f;
#pragma unroll
    for (int k = 0; k < NB; k++) { z[k] = __expf(z[k]); s += z[k]; }
    float r = frcp_(s);
#pragma unroll
    for (int k = 0; k < NB; k++) z[k] *= r;
}

__device__ __forceinline__ half2v pk_(float lo, float hi) {
    fp16x2 p = __builtin_amdgcn_cvt_pkrtz(lo, hi);
    return __builtin_bit_cast(half2v, p);
}
__device__ __forceinline__ half8 cvt8(float4 a0, float4 a1) {
    half2v p0 = pk_(a0.x, a0.y);
    half2v p1 = pk_(a0.z, a0.w);
    half2v p2 = pk_(a1.x, a1.y);
    half2v p3 = pk_(a1.z, a1.w);
    half8 f;
    f[0] = p0[0]; f[1] = p0[1]; f[2] = p1[0]; f[3] = p1[1];
    f[4] = p2[0]; f[5] = p2[1]; f[6] = p3[0]; f[7] = p3[1];
    return f;
}

// ---- named-variable macros (NO addressable aggregates; rule #20) ----
// per 16-row chunk: 8 dwordx4; lane covers k = 32*s + lg*8 .. +7 for s=0..3
#define LOADC(c)                                        \
    A##c##_0 = *(const float4*)(cr##c + 0);             \
    A##c##_1 = *(const float4*)(cr##c + 4);             \
    A##c##_2 = *(const float4*)(cr##c + 32);            \
    A##c##_3 = *(const float4*)(cr##c + 36);            \
    A##c##_4 = *(const float4*)(cr##c + 64);            \
    A##c##_5 = *(const float4*)(cr##c + 68);            \
    A##c##_6 = *(const float4*)(cr##c + 96);            \
    A##c##_7 = *(const float4*)(cr##c + 100);

#define CVTC(c)                                         \
    af0 = cvt8(A##c##_0, A##c##_1);                     \
    af1 = cvt8(A##c##_2, A##c##_3);                     \
    af2 = cvt8(A##c##_4, A##c##_5);                     \
    af3 = cvt8(A##c##_6, A##c##_7);

#define MFMA_S(af, s)                                                           \
    acc0 = __builtin_amdgcn_mfma_f32_16x16x32_f16(af, B0##s, acc0, 0, 0, 0);    \
    acc1 = __builtin_amdgcn_mfma_f32_16x16x32_f16(af, B1##s, acc1, 0, 0, 0);    \
    acc2 = __builtin_amdgcn_mfma_f32_16x16x32_f16(af, B2##s, acc2, 0, 0, 0);    \
    acc3 = __builtin_amdgcn_mfma_f32_16x16x32_f16(af, B3##s, acc3, 0, 0, 0);

// D layout: col = lane&15, row = (lane>>4)*4 + reg  [m89/m91]
// interleaved Z: pos = col*4 + t  <=>  net n = t*16 + col
#define STOREZ(c) {                                                             \
    _Float16* zpw = zbase + (size_t)((c) * 16) * ZSTRIDE;                       \
    _Pragma("unroll")                                                           \
    for (int r = 0; r < 4; r++) {                                               \
        half2v p0 = pk_(acc0[r], acc1[r]);                                      \
        half2v p1 = pk_(acc2[r], acc3[r]);                                      \
        half4v w; w[0] = p0[0]; w[1] = p0[1]; w[2] = p1[0]; w[3] = p1[1];       \
        *(half4v*)(zpw + (size_t)r * ZSTRIDE) = w;                              \
    } }

#define RESET_ACC  acc0 = zf4; acc1 = zf4; acc2 = zf4; acc3 = zf4;

// B frag staging: row l15 of Wt, k = 32*s + lg*8 + j (same formula as A)
#define STAGE_B(Wt, isWd, Q0, Q1, Q2, Q3) {                                     \
    const bool val = (!(isWd)) || (l15 < 15);                                   \
    const float* srcl = (Wt) + (size_t)(val ? l15 : 0) * DM + lg * 8;           \
    float4 q0 = *(const float4*)(srcl + 0),  q1 = *(const float4*)(srcl + 4);   \
    float4 q2 = *(const float4*)(srcl + 32), q3 = *(const float4*)(srcl + 36);  \
    float4 q4 = *(const float4*)(srcl + 64), q5 = *(const float4*)(srcl + 68);  \
    float4 q6 = *(const float4*)(srcl + 96), q7 = *(const float4*)(srcl + 100); \
    Q0 = val ? cvt8(q0, q1) : hz;                                               \
    Q1 = val ? cvt8(q2, q3) : hz;                                               \
    Q2 = val ? cvt8(q4, q5) : hz;                                               \
    Q3 = val ? cvt8(q6, q7) : hz; }

__global__ __launch_bounds__(256, 2) void spline_mfma(
    const float* __restrict__ xin, const float* __restrict__ cond,
    const float* __restrict__ Ww, const float* __restrict__ bw,
    const float* __restrict__ Wh, const float* __restrict__ bh,
    const float* __restrict__ Wd, const float* __restrict__ bd,
    const float* __restrict__ Wl, const float* __restrict__ bl,
    float* __restrict__ out, float* __restrict__ lad, int N)
{
    __shared__ __align__(16) _Float16 Z[BM * ZSTRIDE];

    const int tid  = threadIdx.x;
    const int wave = tid >> 6;
    const int lane = tid & 63;
    const int l15  = lane & 15;
    const int lg   = lane >> 4;
    const size_t blockRow = (size_t)blockIdx.x * BM;
    const size_t gi = blockRow + tid;

    // ---- B FIRST (L2-resident; vmcnt retires in issue order, so putting any
    // HBM load before B would serialize B's cvt behind ~900cyc HBM latency) ----
    half8 hz;
    hz[0]=hz[1]=hz[2]=hz[3]=hz[4]=hz[5]=hz[6]=hz[7] = (_Float16)0.0f;
    half8 B00, B01, B02, B03, B10, B11, B12, B13,
          B20, B21, B22, B23, B30, B31, B32, B33;
    STAGE_B(Ww, false, B00, B01, B02, B03)
    STAGE_B(Wh, false, B10, B11, B12, B13)
    STAGE_B(Wl, false, B20, B21, B22, B23)
    STAGE_B(Wd, true,  B30, B31, B32, B33)

    // ---- full A prefetch: all 32 dwordx4 issued back-to-back (one HBM
    // latency exposure; consumption waits are incremental) ----
    size_t gr0 = blockRow + (size_t)(wave * 64 + l15);
    size_t gr1 = gr0 + 16, gr2 = gr0 + 32, gr3 = gr0 + 48;
    if (gr0 >= (size_t)N) gr0 = (size_t)N - 1;
    if (gr1 >= (size_t)N) gr1 = (size_t)N - 1;
    if (gr2 >= (size_t)N) gr2 = (size_t)N - 1;
    if (gr3 >= (size_t)N) gr3 = (size_t)N - 1;
    const float* cr0 = cond + gr0 * DM + lg * 8;
    const float* cr1 = cond + gr1 * DM + lg * 8;
    const float* cr2 = cond + gr2 * DM + lg * 8;
    const float* cr3 = cond + gr3 * DM + lg * 8;

    float4 A0_0, A0_1, A0_2, A0_3, A0_4, A0_5, A0_6, A0_7;
    float4 A1_0, A1_1, A1_2, A1_3, A1_4, A1_5, A1_6, A1_7;
    float4 A2_0, A2_1, A2_2, A2_3, A2_4, A2_5, A2_6, A2_7;
    float4 A3_0, A3_1, A3_2, A3_3, A3_4, A3_5, A3_6, A3_7;
    LOADC(0)
    LOADC(1)
    LOADC(2)
    LOADC(3)
    float x = xin[gi < (size_t)N ? gi : 0];   // last in vmcnt order (used last)

    // ---- consume in issue order: cvt chunk c waits only on its own loads ----
    const f32x4 zf4 = {0.f, 0.f, 0.f, 0.f};
    f32x4 acc0 = zf4, acc1 = zf4, acc2 = zf4, acc3 = zf4;
    half8 af0, af1, af2, af3;
    _Float16* zbase = &Z[(size_t)(wave * 64 + lg * 4) * ZSTRIDE + l15 * 4];

    CVTC(0)
    MFMA_S(af0, 0) MFMA_S(af1, 1) MFMA_S(af2, 2) MFMA_S(af3, 3)
    STOREZ(0) RESET_ACC
    CVTC(1)
    MFMA_S(af0, 0) MFMA_S(af1, 1) MFMA_S(af2, 2) MFMA_S(af3, 3)
    STOREZ(1) RESET_ACC
    CVTC(2)
    MFMA_S(af0, 0) MFMA_S(af1, 1) MFMA_S(af2, 2) MFMA_S(af3, 3)
    STOREZ(2) RESET_ACC
    CVTC(3)
    MFMA_S(af0, 0) MFMA_S(af1, 1) MFMA_S(af2, 2) MFMA_S(af3, 3)
    STOREZ(3)

    // Wave-local LDS dependency only (wave w writes rows [64w,64w+64), thread
    // tid reads row tid of its own wave) -> no __syncthreads; drain DS queue.
    __builtin_amdgcn_sched_barrier(0);
    asm volatile("s_waitcnt lgkmcnt(0)" ::: "memory");
    __builtin_amdgcn_sched_barrier(0);

    // ---- epilogue: 1 thread = 1 row (proven path) ----
    if (gi >= (size_t)N) return;

    float zw[NB], zh[NB], zl[NB], zd[NB - 1];
    const half4v* zr4 = (const half4v*)&Z[(size_t)tid * ZSTRIDE];
#pragma unroll
    for (int j = 0; j < NB; j++) {
        half4v v = zr4[j];   // interleaved: (zw[j], zh[j], zl[j], zd[j])
        zw[j] = (float)v[0] + bw[j];
        zh[j] = (float)v[1] + bh[j];
        zl[j] = (float)v[2] + bl[j];
        if (j < NB - 1) zd[j] = (float)v[3] + bd[j];
    }

    float xc = fminf(fmaxf(x, -20.0f), 20.0f);

    // widths: module softmax, then spline softmax
    softmax16_m(zw);
    softmax16_nm(zw);
    const float scale = (1.0f - 1e-3f * NB);
    float cw[NB + 1];
    cw[0] = -20.0f;
    float cum = 0.0f;
#pragma unroll
    for (int k = 0; k < NB; k++) {
        cum += 1e-3f + scale * zw[k];
        cw[k + 1] = 40.0f * cum - 20.0f;
    }
    cw[NB] = 20.0f;

    // heights
    softmax16_m(zh);
    softmax16_nm(zh);
    float ch[NB + 1];
    ch[0] = -20.0f;
    cum = 0.0f;
#pragma unroll
    for (int k = 0; k < NB; k++) {
        cum += 1e-3f + scale * zh[k];
        ch[k + 1] = 40.0f * cum - 20.0f;
    }
    ch[NB] = 20.0f;

    // fused searchsorted + gather: one take-predicate chain
    float in_cw = cw[0], cw_hi = cw[1], in_ch = ch[0], ch_hi = ch[1];
    float zl_sel = zl[0], zd_lo = zd[0], zd_hi = zd[0];
#pragma unroll
    for (int k = 1; k < NB; k++) {
        bool take = (xc >= cw[k]);
        in_cw  = take ? cw[k]     : in_cw;
        cw_hi  = take ? cw[k + 1] : cw_hi;
        in_ch  = take ? ch[k]     : in_ch;
        ch_hi  = take ? ch[k + 1] : ch_hi;
        zl_sel = take ? zl[k]     : zl_sel;
        zd_lo  = take ? zd[k - 1] : zd_lo;
        zd_hi  = take ? zd[(k < NB - 1) ? k : NB - 2] : zd_hi;  // k=15 dummy (masked)
    }
    bool firstbin = (xc <  cw[1]);
    bool lastbin  = (xc >= cw[NB - 1]);

    float in_bw = cw_hi - in_cw;
    float in_h  = ch_hi - in_ch;

    // d = MIN_D + softplus([edge, softplus(zd), edge]); edge -> exactly 1.0
    float dk  = firstbin ? 1.0f : (1e-3f + softplus_fast(softplus_fast(zd_lo)));
    float dk1 = lastbin  ? 1.0f : (1e-3f + softplus_fast(softplus_fast(zd_hi)));

    // lambda (double sigmoid)
    float ul  = sigmoid_fast(zl_sel);
    float lam = 0.95f * sigmoid_fast(ul) + 0.025f;

    // rational-linear spline (wa = 1)
    float rbw = frcp_(in_bw);
    float in_delta = in_h * rbw;
    float wb = sqrtf(dk * frcp_(dk1));
    float wc = (lam * dk + (1.0f - lam) * wb * dk1) * frcp_(in_delta);
    float ya = in_ch;
    float yb = in_h + in_ch;
    float yc = ((1.0f - lam) * ya + lam * wb * yb) * frcp_((1.0f - lam) + lam * wb);
    float theta = (xc - in_cw) * rbw;
    bool mlt = (theta <= lam);

    float num = mlt ? (ya * (lam - theta) + wc * yc * theta)
                    : (wc * yc * (1.0f - theta) + wb * yb * (theta - lam));
    float den = mlt ? ((lam - theta) + wc * theta)
                    : (wc * (1.0f - theta) + wb * (theta - lam));
    float sout = num * frcp_(den);
    float dnum = (mlt ? (wc * lam * (yc - ya))
                      : (wb * wc * (1.0f - lam) * (yb - yc))) * rbw;
    float slad = __logf(dnum) - 2.0f * __logf(fabsf(den));

    bool inside = (x >= -20.0f) && (x <= 20.0f);
    out[gi] = inside ? sout : x;
    lad[gi] = inside ? slad : 0.0f;
}

extern "C" void kernel_launch(void* const* d_in, const int* in_sizes, int n_in,
                              void* d_out, int out_size, void* d_ws, size_t ws_size,
                              hipStream_t stream) {
    const float* xin  = (const float*)d_in[0];
    const float* cond = (const float*)d_in[1];
    const float* Ww   = (const float*)d_in[2];
    const float* bwp  = (const float*)d_in[3];
    const float* Wh   = (const float*)d_in[4];
    const float* bhp  = (const float*)d_in[5];
    const float* Wd   = (const float*)d_in[6];
    const float* bdp  = (const float*)d_in[7];
    const float* Wl   = (const float*)d_in[8];
    const float* blp  = (const float*)d_in[9];
    int N = in_sizes[0];  // 32*8192
    float* out = (float*)d_out;
    float* lad = out + N;
    int grid = (N + BM - 1) / BM;
    hipLaunchKernelGGL(spline_mfma, dim3(grid), dim3(256), 0, stream,
                       xin, cond, Ww, bwp, Wh, bhp, Wd, bdp, Wl, blp, out, lad, N);
}

// Round 8
// 35.289 us; speedup vs baseline: 1.3897x; 1.1074x over previous
//
#include <hip/hip_runtime.h>
#include <math.h>

#define NB 16
#define DM 128
#define BM 256
#define ZSTRIDE 68   // halves per Z row: 136 B (8B-aligned b64 access, bank-spread)

typedef _Float16 half8  __attribute__((ext_vector_type(8)));
typedef _Float16 half4v __attribute__((ext_vector_type(4)));
typedef _Float16 half2v __attribute__((ext_vector_type(2)));
typedef __fp16   fp16x2 __attribute__((ext_vector_type(2)));
typedef float    f32x4  __attribute__((ext_vector_type(4)));

__device__ __forceinline__ float frcp_(float x) { return __builtin_amdgcn_rcpf(x); }
__device__ __forceinline__ float softplus_fast(float x) {
    return fmaxf(x, 0.0f) + __logf(1.0f + __expf(-fabsf(x)));
}
__device__ __forceinline__ float sigmoid_fast(float x) {
    return frcp_(1.0f + __expf(-x));
}
__device__ __forceinline__ void softmax16_m(float* z) {
    float m = z[0];
#pragma unroll
    for (int k = 1; k < NB; k++) m = fmaxf(m, z[k]);
    float s = 0.0f;
#pragma unroll
    for (int k = 0; k < NB; k++) { z[k] = __expf(z[k] - m); s += z[k]; }
    float r = frcp_(s);
#pragma unroll
    for (int k = 0; k < NB; k++) z[k] *= r;
}
// outer softmax: inputs in [0,1] (inner softmax output) -> no max-subtract
__device__ __forceinline__ void softmax16_nm(float* z) {
    float s = 0.0f;
#pragma unroll
    for (int k = 0; k < NB; k++) { z[k] = __expf(z[k]); s += z[k]; }
    float r = frcp_(s);
#pragma unroll
    for (int k = 0; k < NB; k++) z[k] *= r;
}

__device__ __forceinline__ half2v pk_(float lo, float hi) {
    fp16x2 p = __builtin_amdgcn_cvt_pkrtz(lo, hi);
    return __builtin_bit_cast(half2v, p);
}
__device__ __forceinline__ half8 cvt8(float4 a0, float4 a1) {
    half2v p0 = pk_(a0.x, a0.y);
    half2v p1 = pk_(a0.z, a0.w);
    half2v p2 = pk_(a1.x, a1.y);
    half2v p3 = pk_(a1.z, a1.w);
    half8 f;
    f[0] = p0[0]; f[1] = p0[1]; f[2] = p1[0]; f[3] = p1[1];
    f[4] = p2[0]; f[5] = p2[1]; f[6] = p3[0]; f[7] = p3[1];
    return f;
}

// ---- named-variable macros (NO addressable aggregates; rule #20) ----
// Full-line pattern: instruction j reads 16 rows x one FULL 64B line each.
// lane (l15,lg): cr = rowbase + lg*4 floats; offsets 16j floats (64B).
// Fragment slot formula (A and B IDENTICAL => HW k-permutation cancels):
//   frag s, elem e: k = 32s + 16*(e>=4) + lg*4 + (e&3)
#define LOADC(P, cr)                                    \
    P##0 = *(const float4*)((cr) + 0);                  \
    P##1 = *(const float4*)((cr) + 16);                 \
    P##2 = *(const float4*)((cr) + 32);                 \
    P##3 = *(const float4*)((cr) + 48);                 \
    P##4 = *(const float4*)((cr) + 64);                 \
    P##5 = *(const float4*)((cr) + 80);                 \
    P##6 = *(const float4*)((cr) + 96);                 \
    P##7 = *(const float4*)((cr) + 112);

#define CVTC(P)                                         \
    af0 = cvt8(P##0, P##1);                             \
    af1 = cvt8(P##2, P##3);                             \
    af2 = cvt8(P##4, P##5);                             \
    af3 = cvt8(P##6, P##7);

#define MFMA_S(af, s)                                                           \
    acc0 = __builtin_amdgcn_mfma_f32_16x16x32_f16(af, B0##s, acc0, 0, 0, 0);    \
    acc1 = __builtin_amdgcn_mfma_f32_16x16x32_f16(af, B1##s, acc1, 0, 0, 0);    \
    acc2 = __builtin_amdgcn_mfma_f32_16x16x32_f16(af, B2##s, acc2, 0, 0, 0);    \
    acc3 = __builtin_amdgcn_mfma_f32_16x16x32_f16(af, B3##s, acc3, 0, 0, 0);

// D layout: col = lane&15, row = (lane>>4)*4 + reg  [m89/m91]
// interleaved Z: pos = col*4 + t  <=>  net n = t*16 + col
#define STOREZ(c) {                                                             \
    _Float16* zpw = zbase + (size_t)((c) * 16) * ZSTRIDE;                       \
    _Pragma("unroll")                                                           \
    for (int r = 0; r < 4; r++) {                                               \
        half2v p0 = pk_(acc0[r], acc1[r]);                                      \
        half2v p1 = pk_(acc2[r], acc3[r]);                                      \
        half4v w; w[0] = p0[0]; w[1] = p0[1]; w[2] = p1[0]; w[3] = p1[1];       \
        *(half4v*)(zpw + (size_t)r * ZSTRIDE) = w;                              \
    } }

#define RESET_ACC  acc0 = zf4; acc1 = zf4; acc2 = zf4; acc3 = zf4;

#define GEMM_CHUNK(P, c)                                                        \
    CVTC(P)                                                                     \
    MFMA_S(af0, 0) MFMA_S(af1, 1) MFMA_S(af2, 2) MFMA_S(af3, 3)                 \
    STOREZ(c) RESET_ACC

// B frag staging: row l15 of Wt, same full-line offsets as A
#define STAGE_B(Wt, isWd, Q0, Q1, Q2, Q3) {                                     \
    const bool val = (!(isWd)) || (l15 < 15);                                   \
    const float* srcl = (Wt) + (size_t)(val ? l15 : 0) * DM + lg * 4;           \
    float4 q0 = *(const float4*)(srcl + 0),  q1 = *(const float4*)(srcl + 16);  \
    float4 q2 = *(const float4*)(srcl + 32), q3 = *(const float4*)(srcl + 48);  \
    float4 q4 = *(const float4*)(srcl + 64), q5 = *(const float4*)(srcl + 80);  \
    float4 q6 = *(const float4*)(srcl + 96), q7 = *(const float4*)(srcl + 112); \
    Q0 = val ? cvt8(q0, q1) : hz;                                               \
    Q1 = val ? cvt8(q2, q3) : hz;                                               \
    Q2 = val ? cvt8(q4, q5) : hz;                                               \
    Q3 = val ? cvt8(q6, q7) : hz; }

// rule #18: inline-asm lgkm drain needs sched_barrier fencing
#define FENCE_LDS                                       \
    __builtin_amdgcn_sched_barrier(0);                  \
    asm volatile("s_waitcnt lgkmcnt(0)" ::: "memory");  \
    __builtin_amdgcn_sched_barrier(0);

// ---- full spline epilogue for one row (reads Z[tid], writes out/lad) ----
#define EPILOGUE(xv, giv)                                                        \
  if ((giv) < (size_t)N) {                                                       \
    float zw[NB], zh[NB], zl[NB], zd[NB - 1];                                    \
    const half4v* zr4 = (const half4v*)&Z[(size_t)tid * ZSTRIDE];                \
    _Pragma("unroll")                                                            \
    for (int j = 0; j < NB; j++) {                                               \
        half4v v = zr4[j];                                                       \
        zw[j] = (float)v[0] + bw[j];                                             \
        zh[j] = (float)v[1] + bh[j];                                             \
        zl[j] = (float)v[2] + bl[j];                                             \
        if (j < NB - 1) zd[j] = (float)v[3] + bd[j];                             \
    }                                                                            \
    float xc = fminf(fmaxf((xv), -20.0f), 20.0f);                                \
    softmax16_m(zw);                                                             \
    softmax16_nm(zw);                                                            \
    const float scale = (1.0f - 1e-3f * NB);                                     \
    float cw[NB + 1];                                                            \
    cw[0] = -20.0f;                                                              \
    float cum = 0.0f;                                                            \
    _Pragma("unroll")                                                            \
    for (int k = 0; k < NB; k++) {                                               \
        cum += 1e-3f + scale * zw[k];                                            \
        cw[k + 1] = 40.0f * cum - 20.0f;                                         \
    }                                                                            \
    cw[NB] = 20.0f;                                                              \
    softmax16_m(zh);                                                             \
    softmax16_nm(zh);                                                            \
    float ch[NB + 1];                                                            \
    ch[0] = -20.0f;                                                              \
    cum = 0.0f;                                                                  \
    _Pragma("unroll")                                                            \
    for (int k = 0; k < NB; k++) {                                               \
        cum += 1e-3f + scale * zh[k];                                            \
        ch[k + 1] = 40.0f * cum - 20.0f;                                         \
    }                                                                            \
    ch[NB] = 20.0f;                                                              \
    float in_cw = cw[0], cw_hi = cw[1], in_ch = ch[0], ch_hi = ch[1];            \
    float zl_sel = zl[0], zd_lo = zd[0], zd_hi = zd[0];                          \
    _Pragma("unroll")                                                            \
    for (int k = 1; k < NB; k++) {                                               \
        bool take = (xc >= cw[k]);                                               \
        in_cw  = take ? cw[k]     : in_cw;                                       \
        cw_hi  = take ? cw[k + 1] : cw_hi;                                       \
        in_ch  = take ? ch[k]     : in_ch;                                       \
        ch_hi  = take ? ch[k + 1] : ch_hi;                                       \
        zl_sel = take ? zl[k]     : zl_sel;                                      \
        zd_lo  = take ? zd[k - 1] : zd_lo;                                       \
        zd_hi  = take ? zd[(k < NB - 1) ? k : NB - 2] : zd_hi;                   \
    }                                                                            \
    bool firstbin = (xc <  cw[1]);                                               \
    bool lastbin  = (xc >= cw[NB - 1]);                                          \
    float in_bw = cw_hi - in_cw;                                                 \
    float in_h  = ch_hi - in_ch;                                                 \
    float dk  = firstbin ? 1.0f : (1e-3f + softplus_fast(softplus_fast(zd_lo))); \
    float dk1 = lastbin  ? 1.0f : (1e-3f + softplus_fast(softplus_fast(zd_hi))); \
    float ul  = sigmoid_fast(zl_sel);                                            \
    float lam = 0.95f * sigmoid_fast(ul) + 0.025f;                               \
    float rbw = frcp_(in_bw);                                                    \
    float in_delta = in_h * rbw;                                                 \
    float wb = sqrtf(dk * frcp_(dk1));                                           \
    float wc = (lam * dk + (1.0f - lam) * wb * dk1) * frcp_(in_delta);           \
    float ya = in_ch;                                                            \
    float yb = in_h + in_ch;                                                     \
    float yc = ((1.0f - lam) * ya + lam * wb * yb) * frcp_((1.0f - lam) + lam * wb); \
    float theta = (xc - in_cw) * rbw;                                            \
    bool mlt = (theta <= lam);                                                   \
    float num = mlt ? (ya * (lam - theta) + wc * yc * theta)                     \
                    : (wc * yc * (1.0f - theta) + wb * yb * (theta - lam));      \
    float den = mlt ? ((lam - theta) + wc * theta)                               \
                    : (wc * (1.0f - theta) + wb * (theta - lam));                \
    float sout = num * frcp_(den);                                               \
    float dnum = (mlt ? (wc * lam * (yc - ya))                                   \
                      : (wb * wc * (1.0f - lam) * (yb - yc))) * rbw;             \
    float slad = __logf(dnum) - 2.0f * __logf(fabsf(den));                       \
    bool inside = ((xv) >= -20.0f) && ((xv) <= 20.0f);                           \
    out[(giv)] = inside ? sout : (xv);                                           \
    lad[(giv)] = inside ? slad : 0.0f;                                           \
  }

__global__ __launch_bounds__(256, 2) void spline_mfma(
    const float* __restrict__ xin, const float* __restrict__ cond,
    const float* __restrict__ Ww, const float* __restrict__ bw,
    const float* __restrict__ Wh, const float* __restrict__ bh,
    const float* __restrict__ Wd, const float* __restrict__ bd,
    const float* __restrict__ Wl, const float* __restrict__ bl,
    float* __restrict__ out, float* __restrict__ lad, int N)
{
    __shared__ __align__(16) _Float16 Z[BM * ZSTRIDE];

    const int tid  = threadIdx.x;
    const int wave = tid >> 6;
    const int lane = tid & 63;
    const int l15  = lane & 15;
    const int lg   = lane >> 4;

    const int nTiles = (N + BM - 1) / BM;
    const int t0 = (int)blockIdx.x;
    const int t1 = t0 + (int)gridDim.x;
    const bool hasT1 = (t1 < nTiles);

    // ---- B FIRST (L2-resident; vmcnt retires in issue order) ----
    half8 hz;
    hz[0]=hz[1]=hz[2]=hz[3]=hz[4]=hz[5]=hz[6]=hz[7] = (_Float16)0.0f;
    half8 B00, B01, B02, B03, B10, B11, B12, B13,
          B20, B21, B22, B23, B30, B31, B32, B33;
    STAGE_B(Ww, false, B00, B01, B02, B03)
    STAGE_B(Wh, false, B10, B11, B12, B13)
    STAGE_B(Wl, false, B20, B21, B22, B23)
    STAGE_B(Wd, true,  B30, B31, B32, B33)

    // ---- tile0: full A prefetch (32 dwordx4, each = full 64B lines) ----
    const size_t bRow0 = (size_t)t0 * BM;
    const size_t gi0 = bRow0 + tid;
    size_t g00 = bRow0 + (size_t)(wave * 64 + l15);
    size_t g01 = g00 + 16, g02 = g00 + 32, g03 = g00 + 48;
    if (g00 >= (size_t)N) g00 = (size_t)N - 1;
    if (g01 >= (size_t)N) g01 = (size_t)N - 1;
    if (g02 >= (size_t)N) g02 = (size_t)N - 1;
    if (g03 >= (size_t)N) g03 = (size_t)N - 1;

    float4 A0_0, A0_1, A0_2, A0_3, A0_4, A0_5, A0_6, A0_7;
    float4 A1_0, A1_1, A1_2, A1_3, A1_4, A1_5, A1_6, A1_7;
    float4 A2_0, A2_1, A2_2, A2_3, A2_4, A2_5, A2_6, A2_7;
    float4 A3_0, A3_1, A3_2, A3_3, A3_4, A3_5, A3_6, A3_7;
    LOADC(A0_, cond + g00 * DM + lg * 4)
    LOADC(A1_, cond + g01 * DM + lg * 4)
    LOADC(A2_, cond + g02 * DM + lg * 4)
    LOADC(A3_, cond + g03 * DM + lg * 4)
    float x0 = xin[gi0 < (size_t)N ? gi0 : 0];

    const f32x4 zf4 = {0.f, 0.f, 0.f, 0.f};
    f32x4 acc0 = zf4, acc1 = zf4, acc2 = zf4, acc3 = zf4;
    half8 af0, af1, af2, af3;
    _Float16* zbase = &Z[(size_t)(wave * 64 + lg * 4) * ZSTRIDE + l15 * 4];

    // ---- GEMM tile0 ----
    GEMM_CHUNK(A0_, 0)
    GEMM_CHUNK(A1_, 1)
    GEMM_CHUNK(A2_, 2)
    GEMM_CHUNK(A3_, 3)

    // ---- cross-tile prefetch: t1 chunks 0-1 in flight during epilogue(t0) ----
    const size_t bRow1 = (size_t)t1 * BM;
    const size_t gi1 = bRow1 + tid;
    size_t g10 = bRow1 + (size_t)(wave * 64 + l15);
    size_t g11 = g10 + 16, g12 = g10 + 32, g13 = g10 + 48;
    if (g10 >= (size_t)N) g10 = (size_t)N - 1;
    if (g11 >= (size_t)N) g11 = (size_t)N - 1;
    if (g12 >= (size_t)N) g12 = (size_t)N - 1;
    if (g13 >= (size_t)N) g13 = (size_t)N - 1;
    float x1 = 0.0f;
    if (hasT1) {
        LOADC(A0_, cond + g10 * DM + lg * 4)
        LOADC(A1_, cond + g11 * DM + lg * 4)
        x1 = xin[gi1 < (size_t)N ? gi1 : 0];
    }

    FENCE_LDS
    EPILOGUE(x0, gi0)

    if (hasT1) {
        LOADC(A2_, cond + g12 * DM + lg * 4)
        LOADC(A3_, cond + g13 * DM + lg * 4)
        GEMM_CHUNK(A0_, 0)
        GEMM_CHUNK(A1_, 1)
        GEMM_CHUNK(A2_, 2)
        GEMM_CHUNK(A3_, 3)
        FENCE_LDS
        EPILOGUE(x1, gi1)
    }
}

extern "C" void kernel_launch(void* const* d_in, const int* in_sizes, int n_in,
                              void* d_out, int out_size, void* d_ws, size_t ws_size,
                              hipStream_t stream) {
    const float* xin  = (const float*)d_in[0];
    const float* cond = (const float*)d_in[1];
    const float* Ww   = (const float*)d_in[2];
    const float* bwp  = (const float*)d_in[3];
    const float* Wh   = (const float*)d_in[4];
    const float* bhp  = (const float*)d_in[5];
    const float* Wd   = (const float*)d_in[6];
    const float* bdp  = (const float*)d_in[7];
    const float* Wl   = (const float*)d_in[8];
    const float* blp  = (const float*)d_in[9];
    int N = in_sizes[0];  // 32*8192
    float* out = (float*)d_out;
    float* lad = out + N;
    int nTiles = (N + BM - 1) / BM;
    int grid = (nTiles + 1) / 2;   // each block handles tiles {b, b+grid}
    hipLaunchKernelGGL(spline_mfma, dim3(grid), dim3(256), 0, stream,
                       xin, cond, Ww, bwp, Wh, bhp, Wd, bdp, Wl, blp, out, lad, N);
}